// Round 10
// baseline (429.072 us; speedup 1.0000x reference)
//
#include <hip/hip_runtime.h>
#include <math.h>

#define NB   2048
#define NS   512
#define NF   15
#define NFP  16                 // padded LDS stride (f=15 is a zero pad)
#define NH   32
#define NTL  24
#define WPB  4                  // waves (= batches) per block
#define CHK  32                 // steps staged per chunk
#define NCHK (NS/CHK)           // 16
#define CELEM (CHK*NF)          // 480 floats per chunk per batch
#define LOADS ((CELEM+63)/64)   // 8 per-lane loads per chunk

__global__ __launch_bounds__(256, 2)
void gru_fused(const float* __restrict__ x,
               const float* __restrict__ Wd,  const float* __restrict__ bd,
               const float* __restrict__ Wih, const float* __restrict__ Whh,
               const float* __restrict__ bih, const float* __restrict__ bhh,
               const float* __restrict__ Wo,  const float* __restrict__ bo,
               float* __restrict__ out)
{
    const int tid = threadIdx.x;
    const int l   = tid & 63;        // lane in wave
    const int w   = tid >> 6;        // wave in block = batch in block
    const int i   = l & 31;          // hidden index (halves redundant, free in issue)
    const int gb  = blockIdx.x * WPB + w;

    __shared__ float Wc[3*NH*NF];            // W_ih @ W_dense (96x15)
    __shared__ float xs[2][WPB][CHK*NFP];    // x staging, padded stride 16

    // cooperative W_comb = W_ih @ W_dense
    for (int idx = tid; idx < 3*NH*NF; idx += 256) {
        const int g = idx / NF, f = idx - g*NF;
        float a = 0.f;
        #pragma unroll
        for (int k = 0; k < NH; ++k) a = fmaf(Wih[g*NH+k], Wd[k*NF+f], a);
        Wc[idx] = a;
    }

    // full recurrent rows for this lane's hidden unit
    float Wr[NH], Wz[NH], Wn[NH];
    #pragma unroll
    for (int j = 0; j < NH; ++j) {
        Wr[j] = Whh[(i       )*NH + j];
        Wz[j] = Whh[(i +   NH)*NH + j];
        Wn[j] = Whh[(i + 2*NH)*NH + j];
    }
    // folded biases
    float br = 0.f, bz = 0.f, bnx = 0.f;
    #pragma unroll
    for (int k = 0; k < NH; ++k) {
        br  = fmaf(Wih[(i       )*NH + k], bd[k], br);
        bz  = fmaf(Wih[(i +   NH)*NH + k], bd[k], bz);
        bnx = fmaf(Wih[(i + 2*NH)*NH + k], bd[k], bnx);
    }
    br  += bih[i]        + bhh[i];
    bz  += bih[i +   NH] + bhh[i +   NH];
    bnx += bih[i + 2*NH];
    const float bnh = bhh[i + 2*NH];
    const float wo  = Wo[i];
    const float bo0 = bo[0];

    __syncthreads();   // Wc ready (only block barrier)

    float Cr[NFP], Cz[NFP], Cn[NFP];
    #pragma unroll
    for (int f = 0; f < NFP; ++f) {
        const bool ok = (f < NF);
        Cr[f] = ok ? Wc[(i       )*NF + f] : 0.f;
        Cz[f] = ok ? Wc[(i +   NH)*NF + f] : 0.f;
        Cn[f] = ok ? Wc[(i + 2*NH)*NF + f] : 0.f;
    }

    // zero the f=15 pad once (C=0 also guards it; hygiene)
    if (l < CHK) { xs[0][w][l*NFP + NF] = 0.f; xs[1][w][l*NFP + NF] = 0.f; }

    const float* xb = x + (size_t)gb * NS * NF;

    // stage chunk 0 (wave-private region, no block barrier needed)
    float st[LOADS];
    #pragma unroll
    for (int k = 0; k < LOADS; ++k) {
        const int e = k*64 + l;
        st[k] = (e < CELEM) ? xb[e] : 0.f;
    }
    #pragma unroll
    for (int k = 0; k < LOADS; ++k) {
        const int e = k*64 + l;
        if (e < CELEM) { const int s = e / NF, f = e - s*NF; xs[0][w][s*NFP + f] = st[k]; }
    }

    float h = 0.f;
    for (int c = 0; c < NCHK; ++c) {
        const float* cur = xs[c & 1][w];
        if (c + 1 < NCHK) {
            #pragma unroll
            for (int k = 0; k < LOADS; ++k) {
                const int e = k*64 + l;
                st[k] = (e < CELEM) ? xb[(c+1)*CELEM + e] : 0.f;
            }
        }
        for (int s = 0; s < CHK; ++s) {
            // x for this step: uniform-address vector reads (broadcast, off-chain)
            const float4* xp = (const float4*)(cur + s*NFP);
            const float4 xa = xp[0], xb4 = xp[1], xc4 = xp[2], xd4 = xp[3];
            float xv[NFP] = { xa.x, xa.y, xa.z, xa.w,  xb4.x, xb4.y, xb4.z, xb4.w,
                              xc4.x, xc4.y, xc4.z, xc4.w, xd4.x, xd4.y, xd4.z, xd4.w };

            // broadcast h via readlane -> SGPRs (no DS on the chain)
            const int hbits = __float_as_int(h);
            float hb[NH];
            #pragma unroll
            for (int j = 0; j < NH; ++j)
                hb[j] = __int_as_float(__builtin_amdgcn_readlane(hbits, j));

            // recurrent matvec: 96 FMAs, 2 accumulators per gate
            float dr0=0.f, dr1=0.f, dz0=0.f, dz1=0.f, dn0=0.f, dn1=0.f;
            #pragma unroll
            for (int j = 0; j < NH; j += 2) {
                dr0 = fmaf(Wr[j],   hb[j],   dr0);
                dr1 = fmaf(Wr[j+1], hb[j+1], dr1);
                dz0 = fmaf(Wz[j],   hb[j],   dz0);
                dz1 = fmaf(Wz[j+1], hb[j+1], dz1);
                dn0 = fmaf(Wn[j],   hb[j],   dn0);
                dn1 = fmaf(Wn[j+1], hb[j+1], dn1);
            }
            // input path (independent of h; scheduler overlaps with chain)
            float gr = br, gz = bz, gnx = bnx;
            #pragma unroll
            for (int f = 0; f < NFP; ++f) {
                gr  = fmaf(Cr[f], xv[f], gr);
                gz  = fmaf(Cz[f], xv[f], gz);
                gnx = fmaf(Cn[f], xv[f], gnx);
            }

            const float ar = gr + (dr0 + dr1);
            const float az = gz + (dz0 + dz1);
            const float dn = dn0 + dn1;
            const float r  = __builtin_amdgcn_rcpf(1.f + __expf(-ar));
            const float z  = __builtin_amdgcn_rcpf(1.f + __expf(-az));
            const float tt = gnx + r*(dn + bnh);
            const float e  = __expf(-2.f*fabsf(tt));
            float th = (1.f - e) * __builtin_amdgcn_rcpf(1.f + e);
            th = copysignf(th, tt);
            h = z*(h - th) + th;          // (1-z)*tanh + z*h

            const int sg = c*CHK + s;
            if (sg >= NS - NTL) {
                float p = wo * h;         // halves identical; reduce within 32-lane half
                p += __int_as_float(__builtin_amdgcn_ds_swizzle(__float_as_int(p), 0x041F));
                p += __int_as_float(__builtin_amdgcn_ds_swizzle(__float_as_int(p), 0x081F));
                p += __int_as_float(__builtin_amdgcn_ds_swizzle(__float_as_int(p), 0x101F));
                p += __int_as_float(__builtin_amdgcn_ds_swizzle(__float_as_int(p), 0x201F));
                p += __int_as_float(__builtin_amdgcn_ds_swizzle(__float_as_int(p), 0x401F));
                if (l == 0) out[gb*NTL + sg - (NS - NTL)] = p + bo0;
            }
        }
        if (c + 1 < NCHK) {
            float* nxt = xs[(c+1) & 1][w];   // wave-private: in-wave ordering suffices
            #pragma unroll
            for (int k = 0; k < LOADS; ++k) {
                const int e = k*64 + l;
                if (e < CELEM) { const int s = e / NF, f = e - s*NF; nxt[s*NFP + f] = st[k]; }
            }
        }
    }
}

extern "C" void kernel_launch(void* const* d_in, const int* in_sizes, int n_in,
                              void* d_out, int out_size, void* d_ws, size_t ws_size,
                              hipStream_t stream) {
    const float* x   = (const float*)d_in[0];
    const float* Wd  = (const float*)d_in[1];
    const float* bd  = (const float*)d_in[2];
    const float* Wih = (const float*)d_in[3];
    const float* Whh = (const float*)d_in[4];
    const float* bih = (const float*)d_in[5];
    const float* bhh = (const float*)d_in[6];
    const float* Wo  = (const float*)d_in[7];
    const float* bo  = (const float*)d_in[8];
    float* out = (float*)d_out;

    dim3 grid(NB / WPB), block(256);
    hipLaunchKernelGGL(gru_fused, grid, block, 0, stream,
                       x, Wd, bd, Wih, Whh, bih, bhh, Wo, bo, out);
}

// Round 12
// 281.732 us; speedup vs baseline: 1.5230x; 1.5230x over previous
//
#include <hip/hip_runtime.h>
#include <math.h>

#define NS   512
#define NF   15
#define NFP  16                 // padded LDS stride
#define NH   32
#define NTL  24
#define BPB  8                  // batches per block (2 per wave)
#define CHK  32                 // steps per staged chunk
#define NCHK (NS/CHK)           // 16
#define PERW (2*CHK*NF)         // 960 floats staged per wave per chunk
#define LOADS (PERW/64)         // 15 per-lane loads per chunk

__global__ __launch_bounds__(256, 1)
void gru_fused(const float* __restrict__ x,
               const float* __restrict__ Wd,  const float* __restrict__ bd,
               const float* __restrict__ Wih, const float* __restrict__ Whh,
               const float* __restrict__ bih, const float* __restrict__ bhh,
               const float* __restrict__ Wo,  const float* __restrict__ bo,
               float* __restrict__ out)
{
    const int tid  = threadIdx.x;
    const int l    = tid & 63;          // lane in wave
    const int w    = tid >> 6;          // wave in block
    const int half = (l >> 5) & 1;      // which batch of this wave
    const int i    = l & 31;            // hidden index
    const int grp  = tid >> 5;          // batch-in-block (0..7)
    const int gb   = blockIdx.x * BPB + grp;

    __shared__ float Wc[3*NH*NF];              // W_ih @ W_dense (96x15)
    __shared__ float xs[2][BPB][CHK*NFP];      // padded x staging
    __shared__ float hx[4][2][40];             // per-(wave,half) h vector, bank-staggered

    // cooperative W_comb = W_ih @ W_dense
    for (int idx = tid; idx < 3*NH*NF; idx += 256) {
        const int g = idx / NF, f = idx - g*NF;
        float a = 0.f;
        #pragma unroll
        for (int k = 0; k < NH; ++k) a = fmaf(Wih[g*NH+k], Wd[k*NF+f], a);
        Wc[idx] = a;
    }
    // zero the f=15 pads in both staging buffers (garbage would poison 0*NaN)
    for (int e = tid; e < 2*BPB*CHK; e += 256) {
        const int buf = e >> 8, rr = e & 255, bb = rr >> 5, s = rr & 31;
        xs[buf][bb][s*NFP + NF] = 0.f;
    }

    // per-lane recurrent rows i, i+32, i+64 of W_hh
    float Wr[NH], Wz[NH], Wn[NH];
    #pragma unroll
    for (int j = 0; j < NH; ++j) {
        Wr[j] = Whh[(i       )*NH + j];
        Wz[j] = Whh[(i +   NH)*NH + j];
        Wn[j] = Whh[(i + 2*NH)*NH + j];
    }
    // folded biases
    float br = 0.f, bz = 0.f, bnx = 0.f;
    #pragma unroll
    for (int k = 0; k < NH; ++k) {
        br  = fmaf(Wih[(i       )*NH + k], bd[k], br);
        bz  = fmaf(Wih[(i +   NH)*NH + k], bd[k], bz);
        bnx = fmaf(Wih[(i + 2*NH)*NH + k], bd[k], bnx);
    }
    br  += bih[i]        + bhh[i];
    bz  += bih[i +   NH] + bhh[i +   NH];
    bnx += bih[i + 2*NH];
    const float bnh = bhh[i + 2*NH];
    const float wo  = Wo[i];
    const float bo0 = bo[0];

    __syncthreads();   // Wc + pads ready (only block barrier)

    float Cr[NFP], Cz[NFP], Cn[NFP];
    #pragma unroll
    for (int f = 0; f < NFP; ++f) {
        const bool ok = (f < NF);
        Cr[f] = ok ? Wc[(i       )*NF + f] : 0.f;
        Cz[f] = ok ? Wc[(i +   NH)*NF + f] : 0.f;
        Cn[f] = ok ? Wc[(i + 2*NH)*NF + f] : 0.f;
    }

    // wave-private staging geometry: e = k*64+l over 2 batches x 480
    const float* xbase = x + (size_t)(blockIdx.x * BPB + w * 2) * NS * NF;
    int goff[LOADS], loff[LOADS], bsel[LOADS];
    #pragma unroll
    for (int k = 0; k < LOADS; ++k) {
        const int e   = k*64 + l;
        const int b   = (e >= 480) ? 1 : 0;
        const int rem = e - 480*b;
        const int s   = rem / NF, f = rem - s*NF;
        goff[k] = b * NS * NF + rem;          // + c*480 per chunk
        loff[k] = s*NFP + f;
        bsel[k] = b;
    }

    float st[LOADS];
    #pragma unroll
    for (int k = 0; k < LOADS; ++k) st[k] = xbase[goff[k]];
    #pragma unroll
    for (int k = 0; k < LOADS; ++k) xs[0][w*2 + bsel[k]][loff[k]] = st[k];

    float h = 0.f;
    for (int c = 0; c < NCHK; ++c) {
        const float* curx = &xs[c & 1][grp][0];
        if (c + 1 < NCHK) {
            #pragma unroll
            for (int k = 0; k < LOADS; ++k)
                st[k] = xbase[goff[k] + (c+1)*CHK*NF];
        }
        #pragma unroll 2
        for (int s = 0; s < CHK; ++s) {
            // publish h, then read the full 32-vector back (broadcast b128 reads).
            // same-wave DS ops complete in order; wave_barrier stops reordering.
            hx[w][half][i] = h;
            __builtin_amdgcn_wave_barrier();
            const float4* hp = (const float4*)(&hx[w][half][0]);
            const float4 h0 = hp[0], h1 = hp[1], h2 = hp[2], h3 = hp[3];
            const float4 h4 = hp[4], h5 = hp[5], h6 = hp[6], h7 = hp[7];
            float hb[NH] = { h0.x,h0.y,h0.z,h0.w, h1.x,h1.y,h1.z,h1.w,
                             h2.x,h2.y,h2.z,h2.w, h3.x,h3.y,h3.z,h3.w,
                             h4.x,h4.y,h4.z,h4.w, h5.x,h5.y,h5.z,h5.w,
                             h6.x,h6.y,h6.z,h6.w, h7.x,h7.y,h7.z,h7.w };
            // x for this step: 4 vector reads (uniform addr within each half)
            const float4* xp = (const float4*)(curx + s*NFP);
            const float4 x0 = xp[0], x1 = xp[1], x2 = xp[2], x3 = xp[3];
            float xv[NFP] = { x0.x,x0.y,x0.z,x0.w, x1.x,x1.y,x1.z,x1.w,
                              x2.x,x2.y,x2.z,x2.w, x3.x,x3.y,x3.z,x3.w };

            // recurrent matvec: 96 FMAs, 2 accumulators per gate
            float dr0=0.f, dr1=0.f, dz0=0.f, dz1=0.f, dn0=0.f, dn1=0.f;
            #pragma unroll
            for (int j = 0; j < NH; j += 2) {
                dr0 = fmaf(Wr[j],   hb[j],   dr0);
                dr1 = fmaf(Wr[j+1], hb[j+1], dr1);
                dz0 = fmaf(Wz[j],   hb[j],   dz0);
                dz1 = fmaf(Wz[j+1], hb[j+1], dz1);
                dn0 = fmaf(Wn[j],   hb[j],   dn0);
                dn1 = fmaf(Wn[j+1], hb[j+1], dn1);
            }
            // input path
            float gr = br, gz = bz, gnx = bnx;
            #pragma unroll
            for (int f = 0; f < NFP; ++f) {
                gr  = fmaf(Cr[f], xv[f], gr);
                gz  = fmaf(Cz[f], xv[f], gz);
                gnx = fmaf(Cn[f], xv[f], gnx);
            }

            const float ar = gr + (dr0 + dr1);
            const float az = gz + (dz0 + dz1);
            const float dn = dn0 + dn1;
            const float r  = __builtin_amdgcn_rcpf(1.f + __expf(-ar));
            const float z  = __builtin_amdgcn_rcpf(1.f + __expf(-az));
            const float tt = gnx + r*(dn + bnh);
            const float e  = __expf(-2.f*fabsf(tt));
            float th = (1.f - e) * __builtin_amdgcn_rcpf(1.f + e);
            th = copysignf(th, tt);
            h = z*(h - th) + th;          // (1-z)*tanh + z*h

            const int sg = c*CHK + s;
            if (sg >= NS - NTL) {
                float p = wo * h;          // reduce within each 32-lane half
                p += __int_as_float(__builtin_amdgcn_ds_swizzle(__float_as_int(p), 0x041F));
                p += __int_as_float(__builtin_amdgcn_ds_swizzle(__float_as_int(p), 0x081F));
                p += __int_as_float(__builtin_amdgcn_ds_swizzle(__float_as_int(p), 0x101F));
                p += __int_as_float(__builtin_amdgcn_ds_swizzle(__float_as_int(p), 0x201F));
                p += __int_as_float(__builtin_amdgcn_ds_swizzle(__float_as_int(p), 0x401F));
                if (i == 0) out[gb*NTL + sg - (NS - NTL)] = p + bo0;
            }
        }
        if (c + 1 < NCHK) {    // wave-private buffers: no block barrier needed
            #pragma unroll
            for (int k = 0; k < LOADS; ++k)
                xs[(c+1) & 1][w*2 + bsel[k]][loff[k]] = st[k];
        }
    }
}

extern "C" void kernel_launch(void* const* d_in, const int* in_sizes, int n_in,
                              void* d_out, int out_size, void* d_ws, size_t ws_size,
                              hipStream_t stream) {
    const float* x   = (const float*)d_in[0];
    const float* Wd  = (const float*)d_in[1];
    const float* bd  = (const float*)d_in[2];
    const float* Wih = (const float*)d_in[3];
    const float* Whh = (const float*)d_in[4];
    const float* bih = (const float*)d_in[5];
    const float* bhh = (const float*)d_in[6];
    const float* Wo  = (const float*)d_in[7];
    const float* bo  = (const float*)d_in[8];
    float* out = (float*)d_out;

    dim3 grid(2048 / BPB), block(256);
    hipLaunchKernelGGL(gru_fused, grid, block, 0, stream,
                       x, Wd, bd, Wih, Whh, bih, bhh, Wo, bo, out);
}